// Round 1
// baseline (78.467 us; speedup 1.0000x reference)
//
#include <hip/hip_runtime.h>
#include <hip/hip_bf16.h>

#define C_DIM 512
#define G_DIM 128
#define ROW_STRIDE 1536   // 3*C
#define ROWS_PER_BLOCK 64

// Order-preserving float->uint mapping (monotonic for all finite floats,
// negatives map below positives). Key 0 is below enc(-inf), safe init.
__device__ __forceinline__ unsigned enc_f32(float f) {
    unsigned b = __float_as_uint(f);
    return (b & 0x80000000u) ? ~b : (b | 0x80000000u);
}
__device__ __forceinline__ float dec_f32(unsigned k) {
    unsigned b = (k & 0x80000000u) ? (k ^ 0x80000000u) : ~k;
    return __uint_as_float(b);
}

__global__ void count_kernel(const int* __restrict__ batch, float* __restrict__ out, int N) {
    int i = blockIdx.x * blockDim.x + threadIdx.x;
    if (i < N) {
        int g = batch[i];
        // count lives in the (currently unused) mean region, col 0
        atomicAdd(reinterpret_cast<int*>(out) + (size_t)g * ROW_STRIDE, 1);
    }
}

__device__ __forceinline__ void flush_seg(float* __restrict__ out, int g, int c0,
                                          const float4& s, const float4& m) {
    float* so = out + (size_t)g * ROW_STRIDE + 1024 + c0;
    atomicAdd(so + 0, s.x);
    atomicAdd(so + 1, s.y);
    atomicAdd(so + 2, s.z);
    atomicAdd(so + 3, s.w);
    unsigned* mo = reinterpret_cast<unsigned*>(out + (size_t)g * ROW_STRIDE + 512 + c0);
    atomicMax(mo + 0, enc_f32(m.x));
    atomicMax(mo + 1, enc_f32(m.y));
    atomicMax(mo + 2, enc_f32(m.z));
    atomicMax(mo + 3, enc_f32(m.w));
}

__global__ __launch_bounds__(128) void pool_kernel(const float* __restrict__ x,
                                                   const int* __restrict__ batch,
                                                   float* __restrict__ out, int N) {
    const int c0 = threadIdx.x * 4;  // 128 threads * 4 ch = 512 channels
    int r0 = blockIdx.x * ROWS_PER_BLOCK;
    int r1 = min(r0 + ROWS_PER_BLOCK, N);
    if (r0 >= N) return;

    float4 s = make_float4(0.f, 0.f, 0.f, 0.f);
    float4 m = make_float4(-INFINITY, -INFINITY, -INFINITY, -INFINITY);
    int cur = batch[r0];

    for (int r = r0; r < r1; ++r) {
        int g = batch[r];
        if (g != cur) {  // sorted batch: boundary -> flush register accumulators
            flush_seg(out, cur, c0, s, m);
            s = make_float4(0.f, 0.f, 0.f, 0.f);
            m = make_float4(-INFINITY, -INFINITY, -INFINITY, -INFINITY);
            cur = g;
        }
        const float4 v = *reinterpret_cast<const float4*>(x + (size_t)r * C_DIM + c0);
        s.x += v.x; s.y += v.y; s.z += v.z; s.w += v.w;
        m.x = fmaxf(m.x, v.x); m.y = fmaxf(m.y, v.y);
        m.z = fmaxf(m.z, v.z); m.w = fmaxf(m.w, v.w);
    }
    flush_seg(out, cur, c0, s, m);
}

__global__ __launch_bounds__(256) void finalize_kernel(float* __restrict__ out) {
    int g = blockIdx.x;
    float* row = out + (size_t)g * ROW_STRIDE;
    __shared__ int scnt;
    if (threadIdx.x == 0) scnt = reinterpret_cast<const int*>(row)[0];
    __syncthreads();
    int cnt = scnt;
    float inv = 1.0f / (float)max(cnt, 1);
    for (int c = threadIdx.x; c < C_DIM; c += 256) {
        float sum = row[1024 + c];
        unsigned k = __float_as_uint(row[512 + c]);
        float mx = (cnt > 0) ? dec_f32(k) : 0.0f;
        row[c] = sum * inv;     // mean (overwrites count slot at c==0, after read)
        row[512 + c] = mx;      // decoded max
        // row[1024 + c] already holds the sum
    }
}

extern "C" void kernel_launch(void* const* d_in, const int* in_sizes, int n_in,
                              void* d_out, int out_size, void* d_ws, size_t ws_size,
                              hipStream_t stream) {
    const float* x     = (const float*)d_in[0];
    const int*   batch = (const int*)d_in[1];
    float* out = (float*)d_out;
    int N = in_sizes[0] / C_DIM;

    hipMemsetAsync(d_out, 0, (size_t)out_size * sizeof(float), stream);

    int nb_cnt = (N + 255) / 256;
    count_kernel<<<nb_cnt, 256, 0, stream>>>(batch, out, N);

    int nb_main = (N + ROWS_PER_BLOCK - 1) / ROWS_PER_BLOCK;
    pool_kernel<<<nb_main, 128, 0, stream>>>(x, batch, out, N);

    finalize_kernel<<<G_DIM, 256, 0, stream>>>(out);
}

// Round 2
// 56.252 us; speedup vs baseline: 1.3949x; 1.3949x over previous
//
#include <hip/hip_runtime.h>
#include <hip/hip_bf16.h>

#define C_DIM 512
#define G_DIM 128
#define ROW_STRIDE 1536   // 3*C
#define ROWS_PER_BLOCK 64
#define CHUNK 8

// Order-preserving float->uint mapping (monotonic for all finite floats,
// negatives map below positives). Key 0 is below enc(-inf), safe init.
__device__ __forceinline__ unsigned enc_f32(float f) {
    unsigned b = __float_as_uint(f);
    return (b & 0x80000000u) ? ~b : (b | 0x80000000u);
}
__device__ __forceinline__ float dec_f32(unsigned k) {
    unsigned b = (k & 0x80000000u) ? (k ^ 0x80000000u) : ~k;
    return __uint_as_float(b);
}

__device__ __forceinline__ void flush_seg(float* __restrict__ out, int g, int c0,
                                          const float4& s, const float4& m,
                                          int run_len, int tid) {
    float* so = out + (size_t)g * ROW_STRIDE + 1024 + c0;
    atomicAdd(so + 0, s.x);
    atomicAdd(so + 1, s.y);
    atomicAdd(so + 2, s.z);
    atomicAdd(so + 3, s.w);
    unsigned* mo = reinterpret_cast<unsigned*>(out + (size_t)g * ROW_STRIDE + 512 + c0);
    atomicMax(mo + 0, enc_f32(m.x));
    atomicMax(mo + 1, enc_f32(m.y));
    atomicMax(mo + 2, enc_f32(m.z));
    atomicMax(mo + 3, enc_f32(m.w));
    if (tid == 0) {  // count lives in the mean region, col 0 (written before mean)
        atomicAdd(reinterpret_cast<int*>(out) + (size_t)g * ROW_STRIDE, run_len);
    }
}

__global__ __launch_bounds__(128) void pool_kernel(const float* __restrict__ x,
                                                   const int* __restrict__ batch,
                                                   float* __restrict__ out, int N) {
    const int tid = threadIdx.x;
    const int c0 = tid * 4;                 // 128 threads * 4 ch = 512 channels
    const int r0 = blockIdx.x * ROWS_PER_BLOCK;
    if (r0 >= N) return;
    const int nrows = min(ROWS_PER_BLOCK, N - r0);

    __shared__ int sb[ROWS_PER_BLOCK];
    if (tid < nrows) sb[tid] = batch[r0 + tid];
    __syncthreads();

    float4 s = make_float4(0.f, 0.f, 0.f, 0.f);
    float4 m = make_float4(-INFINITY, -INFINITY, -INFINITY, -INFINITY);
    int cur = sb[0];
    int run_start = 0;

    int r = 0;
    while (r < nrows) {
        if (nrows - r >= CHUNK && sb[r + CHUNK - 1] == cur) {
            // Fast path: sorted batch + last==cur => whole chunk in one segment.
            // 8 independent float4 loads in flight, then accumulate.
            const float* base = x + (size_t)(r0 + r) * C_DIM + c0;
            float4 v[CHUNK];
#pragma unroll
            for (int j = 0; j < CHUNK; ++j)
                v[j] = *reinterpret_cast<const float4*>(base + (size_t)j * C_DIM);
#pragma unroll
            for (int j = 0; j < CHUNK; ++j) {
                s.x += v[j].x; s.y += v[j].y; s.z += v[j].z; s.w += v[j].w;
                m.x = fmaxf(m.x, v[j].x); m.y = fmaxf(m.y, v[j].y);
                m.z = fmaxf(m.z, v[j].z); m.w = fmaxf(m.w, v[j].w);
            }
            r += CHUNK;
        } else {
            // Slow path (segment boundary in chunk, or tail): row-by-row.
            const int rend = min(r + CHUNK, nrows);
            for (; r < rend; ++r) {
                const int g = sb[r];
                if (g != cur) {
                    flush_seg(out, cur, c0, s, m, r - run_start, tid);
                    s = make_float4(0.f, 0.f, 0.f, 0.f);
                    m = make_float4(-INFINITY, -INFINITY, -INFINITY, -INFINITY);
                    cur = g;
                    run_start = r;
                }
                const float4 v = *reinterpret_cast<const float4*>(
                    x + (size_t)(r0 + r) * C_DIM + c0);
                s.x += v.x; s.y += v.y; s.z += v.z; s.w += v.w;
                m.x = fmaxf(m.x, v.x); m.y = fmaxf(m.y, v.y);
                m.z = fmaxf(m.z, v.z); m.w = fmaxf(m.w, v.w);
            }
        }
    }
    flush_seg(out, cur, c0, s, m, nrows - run_start, tid);
}

__global__ __launch_bounds__(256) void finalize_kernel(float* __restrict__ out) {
    int g = blockIdx.x;
    float* row = out + (size_t)g * ROW_STRIDE;
    __shared__ int scnt;
    if (threadIdx.x == 0) scnt = reinterpret_cast<const int*>(row)[0];
    __syncthreads();
    int cnt = scnt;
    float inv = 1.0f / (float)max(cnt, 1);
    for (int c = threadIdx.x; c < C_DIM; c += 256) {
        float sum = row[1024 + c];
        unsigned k = __float_as_uint(row[512 + c]);
        float mx = (cnt > 0) ? dec_f32(k) : 0.0f;
        row[c] = sum * inv;     // mean (overwrites count slot at c==0, after read)
        row[512 + c] = mx;      // decoded max
        // row[1024 + c] already holds the sum
    }
}

extern "C" void kernel_launch(void* const* d_in, const int* in_sizes, int n_in,
                              void* d_out, int out_size, void* d_ws, size_t ws_size,
                              hipStream_t stream) {
    const float* x     = (const float*)d_in[0];
    const int*   batch = (const int*)d_in[1];
    float* out = (float*)d_out;
    int N = in_sizes[0] / C_DIM;

    hipMemsetAsync(d_out, 0, (size_t)out_size * sizeof(float), stream);

    int nb_main = (N + ROWS_PER_BLOCK - 1) / ROWS_PER_BLOCK;
    pool_kernel<<<nb_main, 128, 0, stream>>>(x, batch, out, N);

    finalize_kernel<<<G_DIM, 256, 0, stream>>>(out);
}